// Round 6
// baseline (280.651 us; speedup 1.0000x reference)
//
#include <hip/hip_runtime.h>
#include <hip/hip_bf16.h>
#include <stdint.h>

// Problem constants
#define B_    32
#define SW_   512
#define SL_   256
#define H_    768
#define NL_   4
#define NOUT_ 400
#define M_    (B_*SL_)   // 8192 pooled rows
#define NPAD_ 448        // N padded to 7 x 64-wide wave slices (covers 400)
#define ROWPAD_ 776      // LDS row stride in shorts (768 + 8 pad)

// B-weight tiled (MFMA fragment-linear) layout for the [448][768] bf16 matrix:
//   elem (n, k) -> ((n>>4)*(H_/8) + (k>>3))*128 + (n&15)*8 + (k&7)
// A 16x32 fragment (n-tile nt, k [k0,+32)) is the contiguous 1024B chunk at
// ((nt*96 + k0/8)*128) shorts; lane L reads 16B at +L*8 shorts.

typedef __attribute__((ext_vector_type(4))) float  f32x4;
typedef __attribute__((ext_vector_type(8))) short  bf16x8;
typedef __attribute__((ext_vector_type(4))) short  bf16x4;

__device__ __forceinline__ unsigned short f2bf(float f) {
  union { float f; unsigned int u; } x; x.f = f;
  unsigned int u = x.u;
  return (unsigned short)((u + 0x7fffu + ((u >> 16) & 1u)) >> 16);
}

// ---------------------------------------------------------------------------
// Kernel 1: cast proj_w -> bf16 fragment-linear layout (pad N to 448).
// 168 blocks x 256 threads x 8 elems = 344064 = 448*768.
// ---------------------------------------------------------------------------
__global__ __launch_bounds__(256) void wcast_kernel(
    const float* __restrict__ projw, unsigned short* __restrict__ wp) {
  const int t = threadIdx.x;
  const int base = blockIdx.x * 2048;
#pragma unroll
  for (int i = 0; i < 8; ++i) {
    int idx = base + i*256 + t;
    int n = idx / H_;
    int k = idx - n*H_;
    float v = (n < NOUT_) ? projw[n*H_ + k] : 0.0f;
    int off = ((n >> 4)*(H_/8) + (k >> 3))*128 + (n & 15)*8 + (k & 7);
    wp[off] = f2bf(v);
  }
}

// ---------------------------------------------------------------------------
// Kernel 2 (fused pool + GEMM): one block per 16 pooled rows. Grid 512
// (2 blocks/CU so one block's phase 2 overlaps the other's phase 1),
// 448 threads (7 waves), LDS 24.8 KB/block.
//  Phase 1: word starts via block reduce + 16-wide serial scan; softmax mix
//   + gamma + ragged mean into padded row-major LDS tile. All 7 waves work
//   via flat (word, column-group) slots: 16 words x 192 groups = 3072.
//  Phase 2: wave w computes out[16 x 64] for N slice [w*64,+64):
//   A-frags ds_read_b128 from LDS, B-frags bf16x8 from wp (L2-resident),
//   MFMA 16x16x32 bf16, depth-2 K-pipeline.
// ---------------------------------------------------------------------------
__global__ __launch_bounds__(448) void fused_kernel(
    const int* __restrict__ lens,
    const float* __restrict__ hidden,
    const float* __restrict__ mixw,
    const float* __restrict__ gamma,
    const unsigned short* __restrict__ wp,
    float* __restrict__ out) {
  const int t  = threadIdx.x;        // 0..447
  const int rt = blockIdx.x;         // 0..511 (16-row tile)
  const int b  = rt >> 4;            // example
  const int j0 = (rt & 15) << 4;     // first of 16 words, <= 240
  const int* lrow = lens + b * SL_;

  __shared__ int s_start[16];
  __shared__ int s_len[16];
  __shared__ int s_wred[7];
  __shared__ __align__(16) unsigned short s_tile[16][ROWPAD_];

  // prefix = sum(lens[b, 0..j0)), j0 <= 240 < 448
  int partial = (t < j0) ? lrow[t] : 0;
#pragma unroll
  for (int off = 32; off > 0; off >>= 1)
    partial += __shfl_down(partial, off);
  if ((t & 63) == 0) s_wred[t >> 6] = partial;
  if (t < 16) s_len[t] = lrow[j0 + t];
  __syncthreads();
  if (t == 0) {
    int s = s_wred[0] + s_wred[1] + s_wred[2] + s_wred[3] + s_wred[4] +
            s_wred[5] + s_wred[6];
#pragma unroll
    for (int w = 0; w < 16; ++w) { s_start[w] = s; s += s_len[w]; }
  }

  // softmax over 4 mix weights (all-thread redundant, trivial)
  float w0 = mixw[0], w1 = mixw[1], w2 = mixw[2], w3 = mixw[3];
  float mx = fmaxf(fmaxf(w0, w1), fmaxf(w2, w3));
  float ew[NL_];
  ew[0] = __expf(w0 - mx); ew[1] = __expf(w1 - mx);
  ew[2] = __expf(w2 - mx); ew[3] = __expf(w3 - mx);
  float esum = ew[0] + ew[1] + ew[2] + ew[3];
  const float gsc = gamma[0] / esum;
  __syncthreads();

  // ---- Phase 1: 3072 flat slots = word w (slot/192) x col-group u
  // (slot%192, floats 4u..4u+3). All 448 threads participate.
#pragma unroll
  for (int i = 0; i < 7; ++i) {
    const int slot = t + i*448;
    if (i == 6 && slot >= 3072) break;
    const int w = slot / 192;
    const int u = slot - w*192;
    const int len = s_len[w];
    const int st  = s_start[w];
    f32x4 acc = {0.0f, 0.0f, 0.0f, 0.0f};
    for (int p = 0; p < len; ++p) {
#pragma unroll
      for (int l = 0; l < NL_; ++l) {
        const f32x4* src = reinterpret_cast<const f32x4*>(
            hidden + ((size_t)(l*B_ + b)*SW_ + (size_t)(st + p)) * H_);
        acc += src[u] * ew[l];
      }
    }
    const float sc = gsc / (float)((len > 0) ? len : 1);
    bf16x4 o;
    o[0] = (short)f2bf(acc[0] * sc);
    o[1] = (short)f2bf(acc[1] * sc);
    o[2] = (short)f2bf(acc[2] * sc);
    o[3] = (short)f2bf(acc[3] * sc);
    *reinterpret_cast<bf16x4*>(&s_tile[w][u*4]) = o;
  }
  __syncthreads();

  // ---- Phase 2: GEMM. Wave w -> N slice [w*64, +64): 1 m-tile x 4 n-tiles.
  const int lane = t & 63;
  const int wv = t >> 6;             // 0..6
  const int nbase = wv * 64;
  const int nt0 = wv * 4;            // B chunk-row base

  f32x4 acc[4];
#pragma unroll
  for (int j = 0; j < 4; ++j)
    acc[j] = (f32x4){0.0f, 0.0f, 0.0f, 0.0f};

  // A fragment: lane L -> A[m = L&15][k = k0 + (L>>4)*8 .. +8]
#define LDA(k0) \
  (*reinterpret_cast<const bf16x8*>(&s_tile[lane & 15][(k0) + (lane >> 4)*8]))
#define LDB(k0, nt) \
  (*reinterpret_cast<const bf16x8*>(wp + ((size_t)((nt0 + (nt))*(H_/8) + ((k0) >> 3)))*128 + lane*8))

  bf16x8 aP, bP[4], aQ, bQ[4];
  aP = LDA(0);
#pragma unroll
  for (int i = 0; i < 4; ++i) bP[i] = LDB(0, i);
  aQ = LDA(32);
#pragma unroll
  for (int i = 0; i < 4; ++i) bQ[i] = LDB(32, i);

  for (int k0 = 64; k0 < H_; k0 += 64) {
#pragma unroll
    for (int nt = 0; nt < 4; ++nt)
      acc[nt] = __builtin_amdgcn_mfma_f32_16x16x32_bf16(aP, bP[nt], acc[nt], 0, 0, 0);
    aP = LDA(k0);
#pragma unroll
    for (int i = 0; i < 4; ++i) bP[i] = LDB(k0, i);
#pragma unroll
    for (int nt = 0; nt < 4; ++nt)
      acc[nt] = __builtin_amdgcn_mfma_f32_16x16x32_bf16(aQ, bQ[nt], acc[nt], 0, 0, 0);
    aQ = LDA(k0 + 32);
#pragma unroll
    for (int i = 0; i < 4; ++i) bQ[i] = LDB(k0 + 32, i);
  }
#pragma unroll
  for (int nt = 0; nt < 4; ++nt) {
    acc[nt] = __builtin_amdgcn_mfma_f32_16x16x32_bf16(aP, bP[nt], acc[nt], 0, 0, 0);
    acc[nt] = __builtin_amdgcn_mfma_f32_16x16x32_bf16(aQ, bQ[nt], acc[nt], 0, 0, 0);
  }
#undef LDA
#undef LDB

  // C/D layout: row = (lane>>4)*4 + r, col = lane&15
  const int r0 = (lane >> 4) * 4;
  const int c = lane & 15;
#pragma unroll
  for (int nt = 0; nt < 4; ++nt) {
    int n = nbase + nt*16 + c;
    if (n < NOUT_) {
      int mrow = rt*16 + r0;
#pragma unroll
      for (int r = 0; r < 4; ++r)
        out[(size_t)(mrow + r)*NOUT_ + n] = acc[nt][r];
    }
  }
}

// ---------------------------------------------------------------------------
extern "C" void kernel_launch(void* const* d_in, const int* in_sizes, int n_in,
                              void* d_out, int out_size, void* d_ws, size_t ws_size,
                              hipStream_t stream) {
  // setup_inputs order: subwords, bert_lens, bert_mask, hidden_states,
  //                     mix_weights, gamma, proj_w
  const int*   lens   = (const int*)d_in[1];
  const float* hidden = (const float*)d_in[3];
  const float* mixw   = (const float*)d_in[4];
  const float* gamma  = (const float*)d_in[5];
  const float* projw  = (const float*)d_in[6];
  float* out = (float*)d_out;

  unsigned short* wp = (unsigned short*)d_ws;   // 448*768*2 = 688128 B

  wcast_kernel<<<dim3(168), dim3(256), 0, stream>>>(projw, wp);
  fused_kernel<<<dim3(512), dim3(448), 0, stream>>>(
      lens, hidden, mixw, gamma, wp, out);
}